// Round 1
// baseline (246.999 us; speedup 1.0000x reference)
//
#include <hip/hip_runtime.h>
#include <math.h>

#define BB 16
#define GG 64
#define PP 8400
#define CC 80
#define KK 13

__device__ __forceinline__ float iou_calc(float gx1,float gy1,float gx2,float gy2,
                                          float px1,float py1,float px2,float py2){
  float iw = fmaxf(fminf(gx2,px2) - fmaxf(gx1,px1), 0.f);
  float ih = fmaxf(fminf(gy2,py2) - fmaxf(gy1,py1), 0.f);
  float inter = iw*ih;
  float ag = fmaxf(gx2-gx1,0.f)*fmaxf(gy2-gy1,0.f);
  float ap = fmaxf(px2-px1,0.f)*fmaxf(py2-py1,0.f);
  return inter / (ag+ap-inter+1e-9f);
}

__device__ __forceinline__ bool better(float va, int ia, float vb, int ib){
  return (va > vb) || (va == vb && ia < ib);
}

// one block per (b,g): top-13 of metrics over P, then mark candidates
__launch_bounds__(256)
__global__ void k_topk(const float* __restrict__ pred_bboxes,
                       const float* __restrict__ pred_scores,
                       const float* __restrict__ priors,
                       const int*   __restrict__ gt_labels,
                       const float* __restrict__ gt_bboxes,
                       const float* __restrict__ pad_flag,
                       int* __restrict__ count, int* __restrict__ cand_g){
  int bg = blockIdx.x;
  int b = bg >> 6, g = bg & 63;
  if (pad_flag[bg] <= 0.f) return;   // pos_mask row identically zero
  int lbl = gt_labels[bg];
  float gx1 = gt_bboxes[bg*4+0], gy1 = gt_bboxes[bg*4+1];
  float gx2 = gt_bboxes[bg*4+2], gy2 = gt_bboxes[bg*4+3];
  int tid = threadIdx.x;

  float v[KK]; int id[KK];
  #pragma unroll
  for (int j=0;j<KK;++j){ v[j] = -1.f; id[j] = 0x7FFFFFFF; }

  const float4* pb = (const float4*)(pred_bboxes + (size_t)b*PP*4);
  const float*  ps = pred_scores + (size_t)b*PP*CC + lbl;

  for (int p = tid; p < PP; p += 256){
    float4 box = pb[p];
    float ov = iou_calc(gx1,gy1,gx2,gy2, box.x,box.y,box.z,box.w);
    float score = ps[(size_t)p*CC];
    float m = score * powf(ov, 6.0f);
    float px = priors[p*4], py = priors[p*4+1];
    float dmin = fminf(fminf(px-gx1, py-gy1), fminf(gx2-px, gy2-py));
    if (!(dmin > 1e-9f)) m = 0.f;          // metrics = align_metric * is_in_gts
    if (better(m, p, v[KK-1], id[KK-1])){
      v[KK-1] = m; id[KK-1] = p;
      #pragma unroll
      for (int j = KK-1; j > 0; --j){
        if (better(v[j], id[j], v[j-1], id[j-1])){
          float tv=v[j]; v[j]=v[j-1]; v[j-1]=tv;
          int   ti=id[j]; id[j]=id[j-1]; id[j-1]=ti;
        }
      }
    }
  }

  __shared__ float sv[256*KK];
  __shared__ int   si[256*KK];
  #pragma unroll
  for (int j=0;j<KK;++j){ sv[tid*KK+j]=v[j]; si[tid*KK+j]=id[j]; }
  __syncthreads();

  for (int off=128; off>=1; off>>=1){
    if (tid < off){
      const float* Av = sv + tid*KK;        const int* Ai = si + tid*KK;
      const float* Bv = sv + (tid+off)*KK;  const int* Bi = si + (tid+off)*KK;
      float mv[KK]; int mi[KK];
      int ai=0, bi=0;
      #pragma unroll
      for (int k=0;k<KK;++k){
        float va=Av[ai]; int ia=Ai[ai];
        float vb=Bv[bi]; int ib=Bi[bi];
        bool ta = better(va,ia,vb,ib);
        mv[k] = ta?va:vb; mi[k] = ta?ia:ib;
        ai += ta?1:0; bi += ta?0:1;
      }
      #pragma unroll
      for (int k=0;k<KK;++k){ sv[tid*KK+k]=mv[k]; si[tid*KK+k]=mi[k]; }
    }
    __syncthreads();
  }

  if (tid < KK){
    int p = si[tid];
    float px = priors[p*4], py = priors[p*4+1];
    float dmin = fminf(fminf(px-gx1, py-gy1), fminf(gx2-px, gy2-py));
    if (dmin > 1e-9f){                     // pos_mask = topk * in_gts * flag
      atomicAdd(&count[b*PP+p], 1);
      atomicExch(&cand_g[b*PP+p], g);
    }
  }
}

// per (b,p): resolve multi-assignment, compute align metric + per-gt maxima
__launch_bounds__(256)
__global__ void k_resolve(const float* __restrict__ pred_bboxes,
                          const float* __restrict__ pred_scores,
                          const int*   __restrict__ gt_labels,
                          const float* __restrict__ gt_bboxes,
                          const int*   __restrict__ count,
                          const int*   __restrict__ cand_g,
                          int* __restrict__ assign_g,
                          float* __restrict__ metric_out,
                          unsigned int* __restrict__ pos_align,
                          unsigned int* __restrict__ pos_ovl){
  int i = blockIdx.x*256 + threadIdx.x;
  if (i >= BB*PP) return;
  int b = i / PP;
  int c = count[i];
  int g = -1;
  float4 box = ((const float4*)pred_bboxes)[i];
  if (c == 1){
    g = cand_g[i];
  } else if (c > 1){
    // pos_mask row replaced by is_max = one_hot(argmax_g overlaps) — ALL g, first-idx ties
    float best = -1.f; int bgidx = 0;
    for (int g2=0; g2<GG; ++g2){
      const float* gb = gt_bboxes + ((size_t)b*GG+g2)*4;
      float ov = iou_calc(gb[0],gb[1],gb[2],gb[3], box.x,box.y,box.z,box.w);
      if (ov > best){ best = ov; bgidx = g2; }
    }
    g = bgidx;
  }
  assign_g[i] = g;
  float m = 0.f;
  if (g >= 0){
    const float* gb = gt_bboxes + ((size_t)b*GG+g)*4;
    float ov = iou_calc(gb[0],gb[1],gb[2],gb[3], box.x,box.y,box.z,box.w);
    int lbl = gt_labels[b*GG+g];
    float score = pred_scores[(size_t)i*CC + lbl];
    m = score * powf(ov, 6.0f);             // align_metric (no in_gts mask here!)
    atomicMax(&pos_align[b*GG+g], __float_as_uint(m));
    atomicMax(&pos_ovl[b*GG+g], __float_as_uint(ov));
  }
  metric_out[i] = m;
}

// per (b,p): write labels, bboxes, fg, and the single nonzero score
__launch_bounds__(256)
__global__ void k_final(const int*   __restrict__ assign_g,
                        const float* __restrict__ metric,
                        const float* __restrict__ pos_align,
                        const float* __restrict__ pos_ovl,
                        const int*   __restrict__ gt_labels,
                        const float* __restrict__ gt_bboxes,
                        float* __restrict__ out){
  int i = blockIdx.x*256 + threadIdx.x;
  if (i >= BB*PP) return;
  int b = i / PP;
  int g = assign_g[i];
  int gi = (g >= 0) ? g : 0;               // argmax of all-zero row -> 0
  int lbl = gt_labels[b*GG+gi]; if (lbl < 0) lbl = 0;

  float* out_labels = out;
  float* out_bboxes = out + BB*PP;
  float* out_scores = out + (size_t)BB*PP*5;
  float* out_fg     = out + (size_t)BB*PP*5 + (size_t)BB*PP*CC;

  out_labels[i] = (float)lbl;
  ((float4*)out_bboxes)[i] = ((const float4*)gt_bboxes)[b*GG+gi];
  out_fg[i] = (g >= 0) ? 1.f : 0.f;
  if (g >= 0){
    float pa = pos_align[b*GG+g];
    float po = pos_ovl[b*GG+g];
    float norm = metric[i] * po / (pa + 1e-7f);
    out_scores[(size_t)i*CC + lbl] = norm;
  }
}

extern "C" void kernel_launch(void* const* d_in, const int* in_sizes, int n_in,
                              void* d_out, int out_size, void* d_ws, size_t ws_size,
                              hipStream_t stream) {
  const float* pred_bboxes = (const float*)d_in[0];
  const float* pred_scores = (const float*)d_in[1];
  const float* priors      = (const float*)d_in[2];
  const int*   gt_labels   = (const int*)d_in[3];
  const float* gt_bboxes   = (const float*)d_in[4];
  const float* pad_flag    = (const float*)d_in[5];
  float* out = (float*)d_out;

  int*   count     = (int*)d_ws;                 // B*P
  int*   cand      = count + BB*PP;              // B*P
  int*   assign    = cand + BB*PP;               // B*P
  float* metric    = (float*)(assign + BB*PP);   // B*P
  unsigned int* pos_align = (unsigned int*)(metric + BB*PP); // B*G
  unsigned int* pos_ovl   = pos_align + BB*GG;               // B*G

  hipMemsetAsync(count, 0, (size_t)BB*PP*sizeof(int), stream);
  hipMemsetAsync(pos_align, 0, (size_t)2*BB*GG*sizeof(unsigned int), stream);
  hipMemsetAsync(out + (size_t)BB*PP*5, 0, (size_t)BB*PP*CC*sizeof(float), stream);

  k_topk<<<BB*GG, 256, 0, stream>>>(pred_bboxes, pred_scores, priors,
                                    gt_labels, gt_bboxes, pad_flag, count, cand);
  int nbp = (BB*PP + 255)/256;
  k_resolve<<<nbp, 256, 0, stream>>>(pred_bboxes, pred_scores, gt_labels, gt_bboxes,
                                     count, cand, assign, metric, pos_align, pos_ovl);
  k_final<<<nbp, 256, 0, stream>>>(assign, metric, (const float*)pos_align,
                                   (const float*)pos_ovl, gt_labels, gt_bboxes, out);
}